// Round 4
// baseline (364.749 us; speedup 1.0000x reference)
//
#include <hip/hip_runtime.h>
#include <stdint.h>

#define PARTITIONABLE 1

namespace {

// ---------------- Threefry-2x32 (constexpr, host+device) ----------------
struct TFPair { uint32_t a, b; };

__host__ __device__ constexpr uint32_t rotl32(uint32_t x, int d) {
  return (x << d) | (x >> (32 - d));
}

__host__ __device__ constexpr TFPair tf2x32(uint32_t k0, uint32_t k1,
                                            uint32_t x0, uint32_t x1) {
  uint32_t k2 = k0 ^ k1 ^ 0x1BD11BDAu;
  x0 += k0; x1 += k1;
  x0 += x1; x1 = rotl32(x1, 13); x1 ^= x0;
  x0 += x1; x1 = rotl32(x1, 15); x1 ^= x0;
  x0 += x1; x1 = rotl32(x1, 26); x1 ^= x0;
  x0 += x1; x1 = rotl32(x1, 6);  x1 ^= x0;
  x0 += k1; x1 += k2 + 1u;
  x0 += x1; x1 = rotl32(x1, 17); x1 ^= x0;
  x0 += x1; x1 = rotl32(x1, 29); x1 ^= x0;
  x0 += x1; x1 = rotl32(x1, 16); x1 ^= x0;
  x0 += x1; x1 = rotl32(x1, 24); x1 ^= x0;
  x0 += k2; x1 += k0 + 2u;
  x0 += x1; x1 = rotl32(x1, 13); x1 ^= x0;
  x0 += x1; x1 = rotl32(x1, 15); x1 ^= x0;
  x0 += x1; x1 = rotl32(x1, 26); x1 ^= x0;
  x0 += x1; x1 = rotl32(x1, 6);  x1 ^= x0;
  x0 += k0; x1 += k1 + 3u;
  x0 += x1; x1 = rotl32(x1, 17); x1 ^= x0;
  x0 += x1; x1 = rotl32(x1, 29); x1 ^= x0;
  x0 += x1; x1 = rotl32(x1, 16); x1 ^= x0;
  x0 += x1; x1 = rotl32(x1, 24); x1 ^= x0;
  x0 += k1; x1 += k2 + 4u;
  x0 += x1; x1 = rotl32(x1, 13); x1 ^= x0;
  x0 += x1; x1 = rotl32(x1, 15); x1 ^= x0;
  x0 += x1; x1 = rotl32(x1, 26); x1 ^= x0;
  x0 += x1; x1 = rotl32(x1, 6);  x1 ^= x0;
  x0 += k2; x1 += k0 + 5u;
  return TFPair{x0, x1};
}

#if PARTITIONABLE
constexpr TFPair KG  = tf2x32(0u, 42u, 0u, 0u);
constexpr TFPair KS  = tf2x32(0u, 42u, 0u, 1u);
constexpr TFPair KA  = tf2x32(0u, 42u, 0u, 2u);
constexpr TFPair KE  = tf2x32(0u, 42u, 0u, 3u);
constexpr TFPair KD  = tf2x32(0u, 42u, 0u, 4u);
constexpr TFPair DK0 = tf2x32(KD.a, KD.b, 0u, 0u);
constexpr TFPair DK1 = tf2x32(KD.a, KD.b, 0u, 1u);
constexpr TFPair DK2 = tf2x32(KD.a, KD.b, 0u, 2u);
#else
constexpr TFPair SP0 = tf2x32(0u, 42u, 0u, 5u);
constexpr TFPair SP1 = tf2x32(0u, 42u, 1u, 6u);
constexpr TFPair SP2 = tf2x32(0u, 42u, 2u, 7u);
constexpr TFPair SP3 = tf2x32(0u, 42u, 3u, 8u);
constexpr TFPair SP4 = tf2x32(0u, 42u, 4u, 9u);
constexpr TFPair KG  = TFPair{SP0.a, SP1.a};
constexpr TFPair KS  = TFPair{SP2.a, SP3.a};
constexpr TFPair KA  = TFPair{SP4.a, SP0.b};
constexpr TFPair KE  = TFPair{SP1.b, SP2.b};
constexpr TFPair KD  = TFPair{SP3.b, SP4.b};
constexpr TFPair DP0 = tf2x32(KD.a, KD.b, 0u, 3u);
constexpr TFPair DP1 = tf2x32(KD.a, KD.b, 1u, 4u);
constexpr TFPair DP2 = tf2x32(KD.a, KD.b, 2u, 5u);
constexpr TFPair DK0 = TFPair{DP0.a, DP1.a};
constexpr TFPair DK1 = TFPair{DP2.a, DP0.b};
constexpr TFPair DK2 = TFPair{DP1.b, DP2.b};
#endif

__device__ __forceinline__ uint32_t rbits(uint32_t k0, uint32_t k1,
                                          uint32_t idx, uint32_t half) {
#if PARTITIONABLE
  TFPair t = tf2x32(k0, k1, 0u, idx);
  return t.a ^ t.b;
#else
  if (idx < half) return tf2x32(k0, k1, idx, idx + half).a;
  return tf2x32(k0, k1, idx - half, idx).b;
#endif
}

__device__ __forceinline__ float bits_to_u01(uint32_t bits) {
  return __uint_as_float((bits >> 9) | 0x3F800000u) - 1.0f;
}

__device__ __forceinline__ float gumbel_u(uint32_t k0, uint32_t k1,
                                          uint32_t idx, uint32_t half) {
  const float mn = 1e-6f;
  const float mx = 1.0f - 1e-6f;
  float f = bits_to_u01(rbits(k0, k1, idx, half));
  return fmaxf(mn, f * (mx - mn) + mn);
}

__device__ __forceinline__ float erfinv_f32(float x) {
  float w = -log1pf(-x * x);
  float p;
  if (w < 5.0f) {
    w -= 2.5f;
    p = 2.81022636e-08f;
    p = fmaf(p, w, 3.43273939e-07f);
    p = fmaf(p, w, -3.5233877e-06f);
    p = fmaf(p, w, -4.39150654e-06f);
    p = fmaf(p, w, 0.00021858087f);
    p = fmaf(p, w, -0.00125372503f);
    p = fmaf(p, w, -0.00417768164f);
    p = fmaf(p, w, 0.246640727f);
    p = fmaf(p, w, 1.50140941f);
  } else {
    w = sqrtf(w) - 3.0f;
    p = -0.000200214257f;
    p = fmaf(p, w, 0.000100950558f);
    p = fmaf(p, w, 0.00134934322f);
    p = fmaf(p, w, -0.00367342844f);
    p = fmaf(p, w, 0.00573950773f);
    p = fmaf(p, w, -0.0076224613f);
    p = fmaf(p, w, 0.00943887047f);
    p = fmaf(p, w, 1.00167406f);
    p = fmaf(p, w, 2.83297682f);
  }
  return p * x;
}

__device__ __forceinline__ float normal_from(uint32_t k0, uint32_t k1,
                                             uint32_t idx, uint32_t half) {
  const float lo = -0x1.fffffep-1f;
  float f = bits_to_u01(rbits(k0, k1, idx, half));
  float u = fmaxf(lo, f * 2.0f + lo);
  return 1.41421356237f * erfinv_f32(u);
}

__device__ __forceinline__ float gelu_f(float x) {
  return 0.5f * x * (1.0f + erff(x / 1.4142135623730951f));
}
__device__ __forceinline__ float sigmoid_f(float x) {
  return 1.0f / (1.0f + expf(-x));
}

__device__ __forceinline__ float wave_sum(float v) {
  #pragma unroll
  for (int m = 32; m > 0; m >>= 1) v += __shfl_xor(v, m);
  return v;
}
__device__ __forceinline__ float wave_max(float v) {
  #pragma unroll
  for (int m = 32; m > 0; m >>= 1) v = fmaxf(v, __shfl_xor(v, m));
  return v;
}
template <int NW>
__device__ __forceinline__ float blk_sum(float v, float* slots) {
  v = wave_sum(v);
  int wid = threadIdx.x >> 6;
  if ((threadIdx.x & 63) == 0) slots[wid] = v;
  __syncthreads();
  float r = slots[0];
  #pragma unroll
  for (int i = 1; i < NW; ++i) r += slots[i];
  return r;
}
template <int NW>
__device__ __forceinline__ float blk_max(float v, float* slots) {
  v = wave_max(v);
  int wid = threadIdx.x >> 6;
  if ((threadIdx.x & 63) == 0) slots[wid] = v;
  __syncthreads();
  float r = slots[0];
  #pragma unroll
  for (int i = 1; i < NW; ++i) r = fmaxf(r, slots[i]);
  return r;
}

// ---------------- params ----------------
struct Params {
  const float *x, *gW1, *gb1, *glnw, *glnb, *gW2, *gb2, *sW1, *sb1, *sW2, *sb2,
      *aW1, *ab1, *aW2, *ab2, *g2f, *semb, *aemb, *decay_f, *decay_b, *tW, *tb,
      *psi, *log_sigma, *step_logits, *noise_scale, *Wk, *mean_w, *mean_b,
      *lv_w, *lv_b, *dW1, *db1, *dlnw, *dlnb, *mW, *mb, *lvW, *lvb;
  float* out;
  float *ps, *ds, *fg, *ctx, *v, *sv, *u, *Pf, *Qf, *Pb, *Qb, *Lf, *Lb, *YH,
      *R1, *gm, *glv, *A, *A2, *At, *At2;
};

// ---------------- device phases ----------------

// two-stage x reduction: per-(b,chunk) partial sums (identical to baseline kL0)
__device__ __forceinline__ void phase_ps(const Params& P, int bid, int tid) {
  int b = bid >> 4, tc = bid & 15;
  const float* xp = P.x + ((size_t)b * 512 + tc * 32) * 256 + tid;
  float s = 0.f;
  for (int i = 0; i < 32; ++i) s += xp[(size_t)i * 256];
  P.ps[(size_t)bid * 256 + tid] = s;
  if (tc == 0) {
    const float* xb = P.x + (size_t)b * 512 * 256 + tid;
    P.ds[b * 256 + tid] = (xb[(size_t)511 * 256] - xb[0]) / 511.0f;
  }
}

// hidden+gates for ONE batch b per block (16 blocks, no redundant matvecs).
// Bit-exact vs the proven quadrant version:
//  - every dot is the same ascending-d fmaf chain starting from the bias
//  - LN / gW2 reductions use the identical blk_sum<4> thread->value mapping
//    (values staged in LDS at index tid)
//  - per-f finalize replicates the reference scalar expression order
//  - Gumbel/threefry indices unchanged
__device__ __forceinline__ void phase_hidgates16(const Params& P, float* smem,
                                                 int b, int tid) {
  float* seqm = smem;            // 256
  float* dif  = smem + 256;      // 256
  float* rawG = smem + 512;      // 256 (becomes hgGs after gelu)
  float* rawS = smem + 768;      // 256 (becomes hgSs)
  float* rawA = smem + 1024;     // 256 (becomes hgAs)
  float* gsl  = smem + 1280;     // 16
  float* gvals= smem + 1296;     // 4
  float* gpv  = smem + 1300;     // 4
  float* s1   = smem + 1304;     // 4
  float* s2   = smem + 1308;     // 4
  // seq_mean from two-stage partials (ascending tc -> bit-exact)
  const float* psb = P.ps + (size_t)(b * 16) * 256 + tid;
  float s = 0.f;
  for (int tc = 0; tc < 16; ++tc) s += psb[(size_t)tc * 256];
  seqm[tid] = s / 512.0f;
  dif[tid] = P.ds[b * 256 + tid];
  __syncthreads();
  // W1 matvecs once: wave0->G, wave1->S, wave2->A; 4 outputs/thread (float4)
  if (tid < 192) {
    int head = tid >> 6;
    int o4 = (tid & 63) * 4;
    const float* W = (head == 0) ? P.gW1 : (head == 1) ? P.sW1 : P.aW1;
    const float* bias = (head == 0) ? P.gb1 : (head == 1) ? P.sb1 : P.ab1;
    const float* src = (head == 2) ? dif : seqm;
    float4 acc = *(const float4*)(bias + o4);
    for (int d0 = 0; d0 < 256; d0 += 8) {
      float4 wv[8];
      #pragma unroll
      for (int q = 0; q < 8; ++q)
        wv[q] = *(const float4*)(W + (size_t)(d0 + q) * 256 + o4);
      #pragma unroll
      for (int q = 0; q < 8; ++q) {
        float sv = src[d0 + q];
        acc.x = fmaf(sv, wv[q].x, acc.x);
        acc.y = fmaf(sv, wv[q].y, acc.y);
        acc.z = fmaf(sv, wv[q].z, acc.z);
        acc.w = fmaf(sv, wv[q].w, acc.w);
      }
    }
    float* dst = (head == 0) ? rawG : (head == 1) ? rawS : rawA;
    dst[o4 + 0] = acc.x;
    dst[o4 + 1] = acc.y;
    dst[o4 + 2] = acc.z;
    dst[o4 + 3] = acc.w;
  }
  __syncthreads();
  // LN(G) with the reference blk_sum mapping, then gelu all three (in place)
  {
    float hG = rawG[tid];
    float mean = blk_sum<4>(hG, s1) / 256.0f;
    float dv = hG - mean;
    float var = blk_sum<4>(dv * dv, s2) / 256.0f;
    hG = dv / sqrtf(var + 1e-5f) * P.glnw[tid] + P.glnb[tid];
    float hS = rawS[tid];
    float hA = rawA[tid];
    rawG[tid] = gelu_f(hG);
    rawS[tid] = gelu_f(hS);
    rawA[tid] = gelu_f(hA);
  }
  __syncthreads();
  // global-regime logits (same blk_sum slot layout as reference)
  float lg[4];
  #pragma unroll
  for (int sx = 0; sx < 4; ++sx)
    lg[sx] = blk_sum<4>(rawG[tid] * P.gW2[tid * 4 + sx], gsl + 4 * sx);
  if (tid < 4) {
    float u = gumbel_u(KG.a, KG.b, (uint32_t)(b * 4 + tid), 32u);
    float g = -logf(-logf(u));
    gvals[tid] = (lg[tid] + P.gb2[tid] + g) / 0.5f;
  }
  __syncthreads();
  if (tid < 4) {
    float mx = fmaxf(fmaxf(gvals[0], gvals[1]), fmaxf(gvals[2], gvals[3]));
    float sum = expf(gvals[0] - mx) + expf(gvals[1] - mx) +
                expf(gvals[2] - mx) + expf(gvals[3] - mx);
    gpv[tid] = expf(gvals[tid] - mx) / sum;
  }
  // fused second layer: thread t owns feature f=t -> 6 sector + 4 asset dots
  // in parallel accumulators (10 loads in flight per iter).
  int f = tid;
  float sacc[6];
  #pragma unroll
  for (int sx = 0; sx < 6; ++sx) sacc[sx] = P.sb2[f * 6 + sx];
  float4 aacc = *(const float4*)(P.ab2 + f * 4);
  const float* swp = P.sW2 + f * 6;
  const float* awp = P.aW2 + f * 4;
  for (int d0 = 0; d0 < 256; d0 += 4) {
    #pragma unroll
    for (int q = 0; q < 4; ++q) {
      int d = d0 + q;
      float hs = rawS[d], ha = rawA[d];
      #pragma unroll
      for (int sx = 0; sx < 6; ++sx)
        sacc[sx] = fmaf(hs, swp[(size_t)d * 1536 + sx], sacc[sx]);
      float4 a4 = *(const float4*)(awp + (size_t)d * 1024);
      aacc.x = fmaf(ha, a4.x, aacc.x);
      aacc.y = fmaf(ha, a4.y, aacc.y);
      aacc.z = fmaf(ha, a4.z, aacc.z);
      aacc.w = fmaf(ha, a4.w, aacc.w);
    }
  }
  float vv[6];
  #pragma unroll
  for (int sx = 0; sx < 6; ++sx) {
    float u = gumbel_u(KS.a, KS.b, (uint32_t)(b * 256 + f) * 6u + sx, 12288u);
    vv[sx] = (sacc[sx] + (-logf(-logf(u)))) / 0.5f;
  }
  float aa[4];
  {
    float u0 = gumbel_u(KA.a, KA.b, (uint32_t)(b * 256 + f) * 4u + 0, 8192u);
    float u1 = gumbel_u(KA.a, KA.b, (uint32_t)(b * 256 + f) * 4u + 1, 8192u);
    float u2 = gumbel_u(KA.a, KA.b, (uint32_t)(b * 256 + f) * 4u + 2, 8192u);
    float u3 = gumbel_u(KA.a, KA.b, (uint32_t)(b * 256 + f) * 4u + 3, 8192u);
    aa[0] = (aacc.x + (-logf(-logf(u0)))) / 0.5f;
    aa[1] = (aacc.y + (-logf(-logf(u1)))) / 0.5f;
    aa[2] = (aacc.z + (-logf(-logf(u2)))) / 0.5f;
    aa[3] = (aacc.w + (-logf(-logf(u3)))) / 0.5f;
  }
  __syncthreads();  // gpv visible
  // finalize (identical scalar sequence to the reference tid<64 body)
  float v0 = vv[0], v1 = vv[1], v2 = vv[2], v3 = vv[3], v4 = vv[4], v5 = vv[5];
  float mx = fmaxf(fmaxf(fmaxf(v0, v1), fmaxf(v2, v3)), fmaxf(v4, v5));
  float e0 = expf(v0 - mx), e1 = expf(v1 - mx), e2 = expf(v2 - mx);
  float e3 = expf(v3 - mx), e4 = expf(v4 - mx), e5 = expf(v5 - mx);
  float ssum = e0 + e1 + e2 + e3 + e4 + e5;
  float sg = (e0 / ssum) * P.semb[0 * 256 + f] + (e1 / ssum) * P.semb[1 * 256 + f] +
             (e2 / ssum) * P.semb[2 * 256 + f] + (e3 / ssum) * P.semb[3 * 256 + f] +
             (e4 / ssum) * P.semb[4 * 256 + f] + (e5 / ssum) * P.semb[5 * 256 + f];
  float a0 = aa[0], a1 = aa[1], a2 = aa[2], a3 = aa[3];
  float amx = fmaxf(fmaxf(a0, a1), fmaxf(a2, a3));
  float x0 = expf(a0 - amx), x1 = expf(a1 - amx);
  float x2 = expf(a2 - amx), x3 = expf(a3 - amx);
  float asum = x0 + x1 + x2 + x3;
  float ag = (x0 / asum) * P.aemb[0 * 256 + f] + (x1 / asum) * P.aemb[1 * 256 + f] +
             (x2 / asum) * P.aemb[2 * 256 + f] + (x3 / asum) * P.aemb[3 * 256 + f];
  float gg = 0.f;
  #pragma unroll
  for (int sx = 0; sx < 4; ++sx) gg = fmaf(gpv[sx], P.g2f[sx * 256 + f], gg);
  P.fg[b * 256 + f] = sigmoid_f(gg + sg + ag);
}

__device__ __forceinline__ void phase_vcompute(const Params& P, int bid2,
                                               int tid) {
  int j = bid2 >> 2, tg = bid2 & 3;
  const float* wp = (j & 1) ? P.lv_w : P.mean_w;
  const float* Wkk = P.Wk + (size_t)(j >> 1) * 65536;
  int wid = tid >> 6, lane = tid & 63;
  float w0 = wp[lane], w1 = wp[64 + lane];
  float svloc = 0.f;
  for (int i = 0; i < 32; ++i) {
    int t = tg * 128 + wid * 32 + i;
    const float* row = Wkk + (size_t)t * 128;
    float s = row[lane] * w0 + row[64 + lane] * w1;
    s = wave_sum(s);
    if (lane == 0) { P.v[j * 512 + t] = s; svloc += s; }
  }
  if (lane == 0) P.sv[j * 16 + tg * 4 + wid] = svloc;
}

__device__ __forceinline__ void phase_ainit_row(const Params& P, float* smem,
                                                int blk, int tid) {
  float* pn = smem;
  float* s1 = smem + 12;
  float* s2 = smem + 16;
  int mh = blk >> 8, h = mh & 3, n = blk & 255, p = tid;
  if (p < 10) pn[p] = P.psi[(size_t)(h * 256 + n) * 10 + p];
  __syncthreads();
  const float* pp = P.psi + (size_t)(h * 256 + p) * 10;
  float s = 0.f;
  #pragma unroll
  for (int e = 0; e < 10; ++e) s = fmaf(pn[e], pp[e], s);
  float logit = s / sqrtf(10.0f);
  uint32_t idx = (uint32_t)blk * 256u + (uint32_t)p;
  float eps = normal_from(KE.a, KE.b, idx, 524288u);
  float val = logit + expf(P.log_sigma[h]) * eps;
  float mx = blk_max<4>(val, s1);
  float e = expf(val - mx);
  float sum = blk_sum<4>(e, s2);
  P.A[(size_t)blk * 256 + p] = e / sum;
}

__device__ __forceinline__ void phase_ctx(const Params& P, float* smem,
                                          int tid) {
  float* s1 = smem;
  float* s2 = smem + 4;
  float c = 0.f;
  for (int b = 0; b < 16; ++b) c += P.fg[b * 256 + tid];
  c /= 16.0f;
  float ss = blk_sum<4>(c * c, s1);
  float cv = c / (sqrtf(ss) + 1e-6f);
  P.ctx[tid] = cv;
  float S = blk_sum<4>(cv, s2);
  if (tid == 0) P.ctx[256] = S;
}

// tiled transpose of A -> At (32x32 tiles, all accesses coalesced)
__device__ __forceinline__ void phase_transA(const Params& P, float* smem,
                                             int blk, int tid) {
  float* tile = smem;  // 32*33
  int mh = blk >> 6;
  int tr = ((blk >> 3) & 7) * 32, tc = (blk & 7) * 32;
  const float* src = P.A + (size_t)mh * 65536;
  float* dst = P.At + (size_t)mh * 65536;
  int lr = tid >> 5, lc = tid & 31;
  #pragma unroll
  for (int p = 0; p < 4; ++p) {
    int r = p * 8 + lr;
    tile[r * 33 + lc] = src[(size_t)(tr + r) * 256 + tc + lc];
  }
  __syncthreads();
  #pragma unroll
  for (int p = 0; p < 4; ++p) {
    int r = p * 8 + lr;
    dst[(size_t)(tc + r) * 256 + tr + lc] = tile[lc * 33 + r];
  }
}

__device__ __forceinline__ void phase_scan1(const Params& P, float* smem,
                                            int ch, int tid) {
  float* vv = smem;  // [8][32]
  int b = ch >> 4, c = ch & 15;
  int d = tid;
  vv[(d >> 5) * 32 + (d & 31)] = P.v[(d >> 5) * 512 + c * 32 + (d & 31)];
  __syncthreads();
  float g = P.fg[b * 256 + d];
  float af = sigmoid_f(P.decay_f[d]);
  float ab = sigmoid_f(P.decay_b[d]);
  float r_gx[32];
  const float* xp = P.x + ((size_t)b * 512 + c * 32) * 256 + d;
  #pragma unroll
  for (int i = 0; i < 32; ++i) r_gx[i] = xp[(size_t)i * 256] * g;
  float h = 0.f, pw = 1.f;
  float Pr[8], Q[8];
  #pragma unroll
  for (int j = 0; j < 8; ++j) { Pr[j] = 0.f; Q[j] = 0.f; }
  #pragma unroll
  for (int i = 0; i < 32; ++i) {
    h = fmaf(af, h, (1.0f - af) * r_gx[i]);
    pw *= af;
    #pragma unroll
    for (int j = 0; j < 8; ++j) {
      float vj = vv[j * 32 + i];
      Pr[j] = fmaf(h, vj, Pr[j]);
      Q[j] = fmaf(pw, vj, Q[j]);
    }
  }
  size_t base = ((size_t)(b * 16 + c) * 8) * 256 + d;
  #pragma unroll
  for (int j = 0; j < 8; ++j) {
    P.Pf[base + j * 256] = Pr[j];
    P.Qf[base + j * 256] = Q[j];
  }
  P.Lf[(b * 16 + c) * 256 + d] = h;
  h = 0.f; pw = 1.f;
  #pragma unroll
  for (int j = 0; j < 8; ++j) { Pr[j] = 0.f; Q[j] = 0.f; }
  #pragma unroll
  for (int i = 31; i >= 0; --i) {
    h = fmaf(ab, h, (1.0f - ab) * r_gx[i]);
    pw *= ab;
    #pragma unroll
    for (int j = 0; j < 8; ++j) {
      float vj = vv[j * 32 + i];
      Pr[j] = fmaf(h, vj, Pr[j]);
      Q[j] = fmaf(pw, vj, Q[j]);
    }
  }
  #pragma unroll
  for (int j = 0; j < 8; ++j) {
    P.Pb[base + j * 256] = Pr[j];
    P.Qb[base + j * 256] = Q[j];
  }
  P.Lb[(b * 16 + c) * 256 + d] = h;
}

__device__ __forceinline__ void phase_scan2(const Params& P, int blk, int tid) {
  int b = blk >> 3, j = blk & 7;
  int d = tid;
  float af = sigmoid_f(P.decay_f[d]);
  float ab = sigmoid_f(P.decay_b[d]);
  float af32 = af, ab32 = ab;
  #pragma unroll
  for (int q = 0; q < 5; ++q) { af32 *= af32; ab32 *= ab32; }
  float acc = 0.f, H = 0.f;
  for (int c = 0; c < 16; ++c) {
    size_t base = ((size_t)(b * 16 + c) * 8 + j) * 256 + d;
    acc += P.Pf[base] + H * P.Qf[base];
    H = P.Lf[(b * 16 + c) * 256 + d] + af32 * H;
  }
  H = 0.f;
  for (int c = 15; c >= 0; --c) {
    size_t base = ((size_t)(b * 16 + c) * 8 + j) * 256 + d;
    acc += P.Pb[base] + H * P.Qb[base];
    H = P.Lb[(b * 16 + c) * 256 + d] + ab32 * H;
  }
  P.u[(b * 8 + j) * 256 + d] = acc;
}

__device__ __forceinline__ void phase_ygemm(const Params& P, float* smem,
                                            int blk32, int tid) {
  float* As = smem;            // 32*33
  float* Bs = smem + 1056;     // 32*33
  float* svs = smem + 2112;    // 8
  int n0 = (blk32 & 7) * 32, m0 = (blk32 >> 3) * 32;
  int tx = tid & 31, ty = tid >> 5;
  if (tid < 8) {
    float ssv = 0.f;
    #pragma unroll
    for (int q = 0; q < 16; ++q) ssv += P.sv[tid * 16 + q];
    svs[tid] = ssv;
  }
  float acc[4] = {0.f, 0.f, 0.f, 0.f};
  for (int k0 = 0; k0 < 256; k0 += 32) {
    #pragma unroll
    for (int l = 0; l < 4; ++l) {
      int e = tid + l * 256, r = e >> 5, cc = e & 31;
      As[r * 33 + cc] = P.u[(size_t)(m0 + r) * 256 + k0 + cc];
      Bs[r * 33 + cc] = P.tW[(size_t)(k0 + r) * 256 + n0 + cc];
    }
    __syncthreads();
    #pragma unroll
    for (int kk = 0; kk < 32; ++kk) {
      float bv = Bs[kk * 33 + tx];
      #pragma unroll
      for (int i = 0; i < 4; ++i)
        acc[i] = fmaf(As[(ty + 8 * i) * 33 + kk], bv, acc[i]);
    }
    __syncthreads();
  }
  int n = n0 + tx;
  float tbn = P.tb[n];
  float mb0 = P.mean_b[0], lb0 = P.lv_b[0];
  #pragma unroll
  for (int i = 0; i < 4; ++i) {
    int row = m0 + ty + 8 * i;
    int b = row >> 3, j = row & 7;
    float val = acc[i] + tbn * svs[j];
    if (j == 0) P.gm[b * 256 + n] = val + mb0;
    else if (j == 1) P.glv[b * 256 + n] = val + lb0;
    else {
      int k = (j >> 1) - 1, proj = j & 1;
      P.YH[k * 8192 + n * 32 + b * 2 + proj] = val;
    }
  }
}

// tiled symmetric mix: 4-row stripe per block (1024 blocks/mix for occupancy).
// All global reads coalesced (A + maintained transpose At). Per-row softmax
// keeps the IDENTICAL blk_max<4>/blk_sum<4> lane mapping (thread tid holds
// column tid) -> bit-identical results.
template <bool WRITE_T>
__device__ __forceinline__ void phase_mix4(const Params& P, float* smem,
                                           int sidx, const float* Ain,
                                           const float* AinT, float* Aout,
                                           float* AoutT, uint32_t dk0,
                                           uint32_t dk1, int blk, int tid) {
  float* vals = smem;             // 4*257
  float* slots = smem + 4 * 257;  // 4*8
  int mh = blk >> 6, r0 = (blk & 63) * 4;
  float alpha = sigmoid_f(P.step_logits[sidx]);
  float ns = P.noise_scale[sidx];
  float S = P.ctx[256];
  int c = tid;
  float cp = P.ctx[c];
  const size_t mbase = (size_t)mh * 65536;
  #pragma unroll
  for (int r = 0; r < 4; ++r) {
    int n = r0 + r;
    float cn = P.ctx[n];
    float o_np = (cn * cp) / fmaxf(cn * S, 1e-6f);
    float o_pn = (cp * cn) / fmaxf(cp * S, 1e-6f);
    uint32_t i_np = (uint32_t)(mh * 65536 + n * 256 + c);
    uint32_t i_pn = (uint32_t)(mh * 65536 + c * 256 + n);
    float a_np = Ain[mbase + (size_t)n * 256 + c];
    float a_pn = AinT[mbase + (size_t)n * 256 + c];
    float m_np = alpha * a_np + (1.0f - alpha) * o_np +
                 ns * normal_from(dk0, dk1, i_np, 524288u);
    float m_pn = alpha * a_pn + (1.0f - alpha) * o_pn +
                 ns * normal_from(dk0, dk1, i_pn, 524288u);
    vals[r * 257 + c] = 0.5f * (m_np + m_pn);
  }
  __syncthreads();
  #pragma unroll
  for (int r = 0; r < 4; ++r) {
    float val = vals[r * 257 + c];
    float mx = blk_max<4>(val, slots + r * 8);
    float e = expf(val - mx);
    float sum = blk_sum<4>(e, slots + r * 8 + 4);
    float o = e / sum;
    Aout[mbase + (size_t)(r0 + r) * 256 + c] = o;
    if (WRITE_T) vals[r * 257 + c] = o;
  }
  if (WRITE_T) {
    __syncthreads();
    float t0 = vals[0 * 257 + c], t1 = vals[1 * 257 + c];
    float t2 = vals[2 * 257 + c], t3 = vals[3 * 257 + c];
    float4* dst = (float4*)(AoutT + mbase + (size_t)c * 256 + r0);
    dst[0] = make_float4(t0, t1, t2, t3);
  }
}

__device__ __forceinline__ void phase_findec(const Params& P, float* smem,
                                             int bid, int tid) {
  float* gmv = smem;       // 256
  float* sl = smem + 256;  // 20
  int b = bid;
  float sm_ = 0.f, sl_ = 0.f;
  for (int mh = 0; mh < 16; ++mh) {
    sm_ += P.R1[(size_t)mh * 8192 + tid * 32 + b * 2];
    sl_ += P.R1[(size_t)mh * 8192 + tid * 32 + b * 2 + 1];
  }
  float gmn = P.gm[b * 256 + tid] + sm_ * (1.0f / 16.0f);
  float gln = P.glv[b * 256 + tid] + sl_ * (1.0f / 16.0f);
  gmv[tid] = gmn;
  float se = expf(gln);
  __syncthreads();
  float sumexp = blk_sum<4>(se, sl);
  float h = 0.f;
  if (tid < 128) {
    h = P.db1[tid];
    for (int n = 0; n < 256; ++n) h = fmaf(gmv[n], P.dW1[n * 128 + tid], h);
    h = gelu_f(h);
  }
  float mean = blk_sum<4>(tid < 128 ? h : 0.f, sl + 4) / 128.0f;
  float dv = (tid < 128) ? h - mean : 0.f;
  float var = blk_sum<4>(dv * dv, sl + 8) / 128.0f;
  float feat = (tid < 128) ? dv / sqrtf(var + 1e-5f) * P.dlnw[tid] + P.dlnb[tid]
                           : 0.f;
  float m_c = blk_sum<4>(tid < 128 ? feat * P.mW[tid] : 0.f, sl + 12) + P.mb[0];
  float lv_c = blk_sum<4>(tid < 128 ? feat * P.lvW[tid] : 0.f, sl + 16) + P.lvb[0];
  if (tid == 0) {
    P.out[b * 2 + 0] = m_c;
    P.out[b * 2 + 1] = logf(expf(lv_c) + sumexp);
  }
}

// ---------------- launch-level kernels (8 launches) ----------------

// k1: ps(0..255) | vcompute(256..287) | ainit(288..4383)
__global__ __launch_bounds__(256) void kPre(Params P) {
  __shared__ float smem[20];
  int bid = blockIdx.x, tid = threadIdx.x;
  if (bid < 256) phase_ps(P, bid, tid);
  else if (bid < 288) phase_vcompute(P, bid - 256, tid);
  else phase_ainit_row(P, smem, bid - 288, tid);
}

// k2: hidgates16(0..15) | transA(16..1039)
__global__ __launch_bounds__(256) void kGate(Params P) {
  __shared__ float smem[1312];
  int bid = blockIdx.x, tid = threadIdx.x;
  if (bid < 16) phase_hidgates16(P, smem, bid, tid);
  else phase_transA(P, smem, bid - 16, tid);
}

// k3: scan1(0..255) | ctx(256)
__global__ __launch_bounds__(256) void kScan(Params P) {
  __shared__ float smem[256];
  int bid = blockIdx.x, tid = threadIdx.x;
  if (bid < 256) phase_scan1(P, smem, bid, tid);
  else phase_ctx(P, smem, tid);
}

// k4: mix0 stripes (0..1023) | scan2 (1024..1151)
__global__ __launch_bounds__(256) void kM0(Params P) {
  __shared__ float smem[1060];
  int bid = blockIdx.x, tid = threadIdx.x;
  if (bid < 1024)
    phase_mix4<true>(P, smem, 0, P.A, P.At, P.A2, P.At2, DK0.a, DK0.b, bid, tid);
  else
    phase_scan2(P, bid - 1024, tid);
}

// k5: mix1 stripes (0..1023) | ygemm (1024..1055)
__global__ __launch_bounds__(256) void kM1(Params P) {
  __shared__ float smem[2120];
  int bid = blockIdx.x, tid = threadIdx.x;
  if (bid < 1024)
    phase_mix4<true>(P, smem, 1, P.A2, P.At2, P.A, P.At, DK1.a, DK1.b, bid, tid);
  else
    phase_ygemm(P, smem, bid - 1024, tid);
}

// k6: mix2 stripes (1024) — no transpose output (horner reads rows only)
__global__ __launch_bounds__(256) void kM2(Params P) {
  __shared__ float smem[1060];
  phase_mix4<false>(P, smem, 2, P.A, P.At, P.A2, nullptr, DK2.a, DK2.b,
                    blockIdx.x, threadIdx.x);
}

// k7: fused 3-hop horner. Column-split: block = (mh, 2-col group); R columns
// stay in LDS across hops (A.R is column-independent). Bit-exact chains.
__global__ __launch_bounds__(256) void kHor(Params P) {
  __shared__ float Rc[512];  // [256 k][2 c]
  int bid = blockIdx.x, tid = threadIdx.x;
  int mh = bid >> 4, c0 = (bid & 15) * 2;
  const float* Ab = P.A2 + (size_t)mh * 65536;
  const float4* Arow = (const float4*)(Ab + (size_t)tid * 256);
  const float* Y2 = P.YH + 2 * 8192;
  Rc[tid * 2 + 0] = Y2[tid * 32 + c0 + 0];
  Rc[tid * 2 + 1] = Y2[tid * 32 + c0 + 1];
  __syncthreads();
  #pragma unroll
  for (int hop = 0; hop < 3; ++hop) {
    float acc0 = 0.f, acc1 = 0.f;
    const float4* Rc4 = (const float4*)Rc;
    for (int k4 = 0; k4 < 64; ++k4) {
      float4 a = Arow[k4];
      float4 r01 = Rc4[k4 * 2];
      float4 r23 = Rc4[k4 * 2 + 1];
      acc0 = fmaf(a.x, r01.x, acc0); acc1 = fmaf(a.x, r01.y, acc1);
      acc0 = fmaf(a.y, r01.z, acc0); acc1 = fmaf(a.y, r01.w, acc1);
      acc0 = fmaf(a.z, r23.x, acc0); acc1 = fmaf(a.z, r23.y, acc1);
      acc0 = fmaf(a.w, r23.z, acc0); acc1 = fmaf(a.w, r23.w, acc1);
    }
    if (hop == 0) {
      acc0 += P.YH[8192 + tid * 32 + c0 + 0];
      acc1 += P.YH[8192 + tid * 32 + c0 + 1];
    } else if (hop == 1) {
      acc0 += P.YH[tid * 32 + c0 + 0];
      acc1 += P.YH[tid * 32 + c0 + 1];
    }
    __syncthreads();
    Rc[tid * 2 + 0] = acc0;
    Rc[tid * 2 + 1] = acc1;
    __syncthreads();
  }
  P.R1[(size_t)mh * 8192 + (size_t)tid * 32 + c0 + 0] = Rc[tid * 2 + 0];
  P.R1[(size_t)mh * 8192 + (size_t)tid * 32 + c0 + 1] = Rc[tid * 2 + 1];
}

// k8: final + decoder (16 blocks)
__global__ __launch_bounds__(256) void kFin(Params P) {
  __shared__ float smem[276];
  phase_findec(P, smem, blockIdx.x, threadIdx.x);
}

// workspace layout (float offsets)
constexpr size_t O_FG = 0;            // 4096
constexpr size_t O_CTX = 4096;        // 384 (uses 257)
constexpr size_t O_V = 4480;          // 4096
constexpr size_t O_SV = 8576;         // 128 (per-wave partials)
constexpr size_t O_U = 8704;          // 32768
constexpr size_t O_PF = 41472;        // 524288
constexpr size_t O_QF = 565760;       // 524288
constexpr size_t O_PB = 1090048;      // 524288
constexpr size_t O_QB = 1614336;      // 524288
constexpr size_t O_LF = 2138624;      // 65536
constexpr size_t O_LB = 2204160;      // 65536
constexpr size_t O_YH = 2269696;      // 24576
constexpr size_t O_R1 = 2294272;      // 131072
constexpr size_t O_GM = 2425344;      // 4096
constexpr size_t O_GLV = 2429440;     // 4096
constexpr size_t O_A = 2433536;       // 1048576
constexpr size_t O_A2 = 3482112;      // 1048576
constexpr size_t O_AT = 4530688;      // 1048576
constexpr size_t O_AT2 = 5579264;     // 1048576
constexpr size_t O_PS = 6627840;      // 65536
constexpr size_t O_DS = 6693376;      // 4096
// end = 6697472 floats ~= 26.8 MB

}  // namespace

extern "C" void kernel_launch(void* const* d_in, const int* in_sizes, int n_in,
                              void* d_out, int out_size, void* d_ws,
                              size_t ws_size, hipStream_t stream) {
  (void)in_sizes; (void)n_in; (void)out_size; (void)ws_size;
  float* w = (float*)d_ws;
  Params prm;
  prm.x = (const float*)d_in[0];
  prm.gW1 = (const float*)d_in[1];
  prm.gb1 = (const float*)d_in[2];
  prm.glnw = (const float*)d_in[3];
  prm.glnb = (const float*)d_in[4];
  prm.gW2 = (const float*)d_in[5];
  prm.gb2 = (const float*)d_in[6];
  prm.sW1 = (const float*)d_in[7];
  prm.sb1 = (const float*)d_in[8];
  prm.sW2 = (const float*)d_in[9];
  prm.sb2 = (const float*)d_in[10];
  prm.aW1 = (const float*)d_in[11];
  prm.ab1 = (const float*)d_in[12];
  prm.aW2 = (const float*)d_in[13];
  prm.ab2 = (const float*)d_in[14];
  prm.g2f = (const float*)d_in[18];
  prm.semb = (const float*)d_in[19];
  prm.aemb = (const float*)d_in[20];
  prm.decay_f = (const float*)d_in[21];
  prm.decay_b = (const float*)d_in[22];
  prm.tW = (const float*)d_in[23];
  prm.tb = (const float*)d_in[24];
  prm.psi = (const float*)d_in[25];
  prm.log_sigma = (const float*)d_in[26];
  prm.step_logits = (const float*)d_in[27];
  prm.noise_scale = (const float*)d_in[28];
  prm.Wk = (const float*)d_in[29];
  prm.mean_w = (const float*)d_in[30];
  prm.mean_b = (const float*)d_in[31];
  prm.lv_w = (const float*)d_in[32];
  prm.lv_b = (const float*)d_in[33];
  prm.dW1 = (const float*)d_in[34];
  prm.db1 = (const float*)d_in[35];
  prm.dlnw = (const float*)d_in[36];
  prm.dlnb = (const float*)d_in[37];
  prm.mW = (const float*)d_in[38];
  prm.mb = (const float*)d_in[39];
  prm.lvW = (const float*)d_in[40];
  prm.lvb = (const float*)d_in[41];
  prm.out = (float*)d_out;
  prm.fg = w + O_FG;
  prm.ctx = w + O_CTX;
  prm.v = w + O_V;
  prm.sv = w + O_SV;
  prm.u = w + O_U;
  prm.Pf = w + O_PF;
  prm.Qf = w + O_QF;
  prm.Pb = w + O_PB;
  prm.Qb = w + O_QB;
  prm.Lf = w + O_LF;
  prm.Lb = w + O_LB;
  prm.YH = w + O_YH;
  prm.R1 = w + O_R1;
  prm.gm = w + O_GM;
  prm.glv = w + O_GLV;
  prm.A = w + O_A;
  prm.A2 = w + O_A2;
  prm.At = w + O_AT;
  prm.At2 = w + O_AT2;
  prm.ps = w + O_PS;
  prm.ds = w + O_DS;

  kPre<<<4384, 256, 0, stream>>>(prm);
  kGate<<<1040, 256, 0, stream>>>(prm);
  kScan<<<257, 256, 0, stream>>>(prm);
  kM0<<<1152, 256, 0, stream>>>(prm);
  kM1<<<1056, 256, 0, stream>>>(prm);
  kM2<<<1024, 256, 0, stream>>>(prm);
  kHor<<<256, 256, 0, stream>>>(prm);
  kFin<<<16, 256, 0, stream>>>(prm);
}

// Round 5
// 292.047 us; speedup vs baseline: 1.2489x; 1.2489x over previous
//
#include <hip/hip_runtime.h>
#include <stdint.h>

#define PARTITIONABLE 1

namespace {

// ---------------- Threefry-2x32 (constexpr, host+device) ----------------
struct TFPair { uint32_t a, b; };

__host__ __device__ constexpr uint32_t rotl32(uint32_t x, int d) {
  return (x << d) | (x >> (32 - d));
}

__host__ __device__ constexpr TFPair tf2x32(uint32_t k0, uint32_t k1,
                                            uint32_t x0, uint32_t x1) {
  uint32_t k2 = k0 ^ k1 ^ 0x1BD11BDAu;
  x0 += k0; x1 += k1;
  x0 += x1; x1 = rotl32(x1, 13); x1 ^= x0;
  x0 += x1; x1 = rotl32(x1, 15); x1 ^= x0;
  x0 += x1; x1 = rotl32(x1, 26); x1 ^= x0;
  x0 += x1; x1 = rotl32(x1, 6);  x1 ^= x0;
  x0 += k1; x1 += k2 + 1u;
  x0 += x1; x1 = rotl32(x1, 17); x1 ^= x0;
  x0 += x1; x1 = rotl32(x1, 29); x1 ^= x0;
  x0 += x1; x1 = rotl32(x1, 16); x1 ^= x0;
  x0 += x1; x1 = rotl32(x1, 24); x1 ^= x0;
  x0 += k2; x1 += k0 + 2u;
  x0 += x1; x1 = rotl32(x1, 13); x1 ^= x0;
  x0 += x1; x1 = rotl32(x1, 15); x1 ^= x0;
  x0 += x1; x1 = rotl32(x1, 26); x1 ^= x0;
  x0 += x1; x1 = rotl32(x1, 6);  x1 ^= x0;
  x0 += k0; x1 += k1 + 3u;
  x0 += x1; x1 = rotl32(x1, 17); x1 ^= x0;
  x0 += x1; x1 = rotl32(x1, 29); x1 ^= x0;
  x0 += x1; x1 = rotl32(x1, 16); x1 ^= x0;
  x0 += x1; x1 = rotl32(x1, 24); x1 ^= x0;
  x0 += k1; x1 += k2 + 4u;
  x0 += x1; x1 = rotl32(x1, 13); x1 ^= x0;
  x0 += x1; x1 = rotl32(x1, 15); x1 ^= x0;
  x0 += x1; x1 = rotl32(x1, 26); x1 ^= x0;
  x0 += x1; x1 = rotl32(x1, 6);  x1 ^= x0;
  x0 += k2; x1 += k0 + 5u;
  return TFPair{x0, x1};
}

#if PARTITIONABLE
constexpr TFPair KG  = tf2x32(0u, 42u, 0u, 0u);
constexpr TFPair KS  = tf2x32(0u, 42u, 0u, 1u);
constexpr TFPair KA  = tf2x32(0u, 42u, 0u, 2u);
constexpr TFPair KE  = tf2x32(0u, 42u, 0u, 3u);
constexpr TFPair KD  = tf2x32(0u, 42u, 0u, 4u);
constexpr TFPair DK0 = tf2x32(KD.a, KD.b, 0u, 0u);
constexpr TFPair DK1 = tf2x32(KD.a, KD.b, 0u, 1u);
constexpr TFPair DK2 = tf2x32(KD.a, KD.b, 0u, 2u);
#else
constexpr TFPair SP0 = tf2x32(0u, 42u, 0u, 5u);
constexpr TFPair SP1 = tf2x32(0u, 42u, 1u, 6u);
constexpr TFPair SP2 = tf2x32(0u, 42u, 2u, 7u);
constexpr TFPair SP3 = tf2x32(0u, 42u, 3u, 8u);
constexpr TFPair SP4 = tf2x32(0u, 42u, 4u, 9u);
constexpr TFPair KG  = TFPair{SP0.a, SP1.a};
constexpr TFPair KS  = TFPair{SP2.a, SP3.a};
constexpr TFPair KA  = TFPair{SP4.a, SP0.b};
constexpr TFPair KE  = TFPair{SP1.b, SP2.b};
constexpr TFPair KD  = TFPair{SP3.b, SP4.b};
constexpr TFPair DP0 = tf2x32(KD.a, KD.b, 0u, 3u);
constexpr TFPair DP1 = tf2x32(KD.a, KD.b, 1u, 4u);
constexpr TFPair DP2 = tf2x32(KD.a, KD.b, 2u, 5u);
constexpr TFPair DK0 = TFPair{DP0.a, DP1.a};
constexpr TFPair DK1 = TFPair{DP2.a, DP0.b};
constexpr TFPair DK2 = TFPair{DP1.b, DP2.b};
#endif

__device__ __forceinline__ uint32_t rbits(uint32_t k0, uint32_t k1,
                                          uint32_t idx, uint32_t half) {
#if PARTITIONABLE
  TFPair t = tf2x32(k0, k1, 0u, idx);
  return t.a ^ t.b;
#else
  if (idx < half) return tf2x32(k0, k1, idx, idx + half).a;
  return tf2x32(k0, k1, idx - half, idx).b;
#endif
}

__device__ __forceinline__ float bits_to_u01(uint32_t bits) {
  return __uint_as_float((bits >> 9) | 0x3F800000u) - 1.0f;
}

__device__ __forceinline__ float gumbel_u(uint32_t k0, uint32_t k1,
                                          uint32_t idx, uint32_t half) {
  const float mn = 1e-6f;
  const float mx = 1.0f - 1e-6f;
  float f = bits_to_u01(rbits(k0, k1, idx, half));
  return fmaxf(mn, f * (mx - mn) + mn);
}

__device__ __forceinline__ float erfinv_f32(float x) {
  float w = -log1pf(-x * x);
  float p;
  if (w < 5.0f) {
    w -= 2.5f;
    p = 2.81022636e-08f;
    p = fmaf(p, w, 3.43273939e-07f);
    p = fmaf(p, w, -3.5233877e-06f);
    p = fmaf(p, w, -4.39150654e-06f);
    p = fmaf(p, w, 0.00021858087f);
    p = fmaf(p, w, -0.00125372503f);
    p = fmaf(p, w, -0.00417768164f);
    p = fmaf(p, w, 0.246640727f);
    p = fmaf(p, w, 1.50140941f);
  } else {
    w = sqrtf(w) - 3.0f;
    p = -0.000200214257f;
    p = fmaf(p, w, 0.000100950558f);
    p = fmaf(p, w, 0.00134934322f);
    p = fmaf(p, w, -0.00367342844f);
    p = fmaf(p, w, 0.00573950773f);
    p = fmaf(p, w, -0.0076224613f);
    p = fmaf(p, w, 0.00943887047f);
    p = fmaf(p, w, 1.00167406f);
    p = fmaf(p, w, 2.83297682f);
  }
  return p * x;
}

__device__ __forceinline__ float normal_from(uint32_t k0, uint32_t k1,
                                             uint32_t idx, uint32_t half) {
  const float lo = -0x1.fffffep-1f;
  float f = bits_to_u01(rbits(k0, k1, idx, half));
  float u = fmaxf(lo, f * 2.0f + lo);
  return 1.41421356237f * erfinv_f32(u);
}

__device__ __forceinline__ float gelu_f(float x) {
  return 0.5f * x * (1.0f + erff(x / 1.4142135623730951f));
}
__device__ __forceinline__ float sigmoid_f(float x) {
  return 1.0f / (1.0f + expf(-x));
}

__device__ __forceinline__ float wave_sum(float v) {
  #pragma unroll
  for (int m = 32; m > 0; m >>= 1) v += __shfl_xor(v, m);
  return v;
}
__device__ __forceinline__ float wave_max(float v) {
  #pragma unroll
  for (int m = 32; m > 0; m >>= 1) v = fmaxf(v, __shfl_xor(v, m));
  return v;
}
template <int NW>
__device__ __forceinline__ float blk_sum(float v, float* slots) {
  v = wave_sum(v);
  int wid = threadIdx.x >> 6;
  if ((threadIdx.x & 63) == 0) slots[wid] = v;
  __syncthreads();
  float r = slots[0];
  #pragma unroll
  for (int i = 1; i < NW; ++i) r += slots[i];
  return r;
}
template <int NW>
__device__ __forceinline__ float blk_max(float v, float* slots) {
  v = wave_max(v);
  int wid = threadIdx.x >> 6;
  if ((threadIdx.x & 63) == 0) slots[wid] = v;
  __syncthreads();
  float r = slots[0];
  #pragma unroll
  for (int i = 1; i < NW; ++i) r = fmaxf(r, slots[i]);
  return r;
}

// ---------------- params ----------------
struct Params {
  const float *x, *gW1, *gb1, *glnw, *glnb, *gW2, *gb2, *sW1, *sb1, *sW2, *sb2,
      *aW1, *ab1, *aW2, *ab2, *g2f, *semb, *aemb, *decay_f, *decay_b, *tW, *tb,
      *psi, *log_sigma, *step_logits, *noise_scale, *Wk, *mean_w, *mean_b,
      *lv_w, *lv_b, *dW1, *db1, *dlnw, *dlnb, *mW, *mb, *lvW, *lvb;
  float* out;
  float *fg, *ctx, *v, *sv, *u, *Pf, *Qf, *Pb, *Qb, *Lf, *Lb, *YH,
      *R1, *gm, *glv, *A, *A2, *At, *At2, *hgS, *hgA, *lvS, *lvA, *gpv;
};

// ---------------- device phases ----------------

// W1 batched over columns: block = (head, b), thread = output column.
// seq_mean computed directly from x with the identical two-level (16x32)
// summation order (proven bit-exact in round 2). Each output's dot is the
// same ascending-d fmaf chain from the bias. G-head finishes LN + gW2 + gpv
// with the identical blk_sum<4> thread->value mappings.
__device__ __forceinline__ void phase_w1head(const Params& P, float* smem,
                                             int blk, int tid) {
  float* src  = smem;          // 256
  float* s1   = smem + 256;    // 4
  float* s2   = smem + 260;    // 4
  float* gsl  = smem + 264;    // 16
  float* gvals= smem + 280;    // 4
  int head = blk >> 4, b = blk & 15;
  const float* xb = P.x + (size_t)b * 512 * 256 + tid;
  if (head < 2) {
    float s = 0.f;
    for (int tc = 0; tc < 16; ++tc) {
      float ps = 0.f;
      #pragma unroll
      for (int i = 0; i < 32; ++i) ps += xb[(size_t)(tc * 32 + i) * 256];
      s += ps;
    }
    src[tid] = s / 512.0f;
  } else {
    src[tid] = (xb[(size_t)511 * 256] - xb[0]) / 511.0f;
  }
  __syncthreads();
  const float* W = (head == 0) ? P.gW1 : (head == 1) ? P.sW1 : P.aW1;
  const float* bias = (head == 0) ? P.gb1 : (head == 1) ? P.sb1 : P.ab1;
  float acc = bias[tid];
  #pragma unroll 8
  for (int d = 0; d < 256; ++d)
    acc = fmaf(src[d], W[(size_t)d * 256 + tid], acc);
  if (head == 1) { P.hgS[b * 256 + tid] = gelu_f(acc); return; }
  if (head == 2) { P.hgA[b * 256 + tid] = gelu_f(acc); return; }
  // head G: LN (reference blk_sum mapping) + gelu + gW2 logits + gpv
  float mean = blk_sum<4>(acc, s1) / 256.0f;
  float dv = acc - mean;
  float var = blk_sum<4>(dv * dv, s2) / 256.0f;
  float hg = gelu_f(dv / sqrtf(var + 1e-5f) * P.glnw[tid] + P.glnb[tid]);
  float lg[4];
  #pragma unroll
  for (int sx = 0; sx < 4; ++sx)
    lg[sx] = blk_sum<4>(hg * P.gW2[tid * 4 + sx], gsl + 4 * sx);
  if (tid < 4) {
    float u = gumbel_u(KG.a, KG.b, (uint32_t)(b * 4 + tid), 32u);
    float g = -logf(-logf(u));
    gvals[tid] = (lg[tid] + P.gb2[tid] + g) / 0.5f;
  }
  __syncthreads();
  if (tid < 4) {
    float mx = fmaxf(fmaxf(gvals[0], gvals[1]), fmaxf(gvals[2], gvals[3]));
    float sum = expf(gvals[0] - mx) + expf(gvals[1] - mx) +
                expf(gvals[2] - mx) + expf(gvals[3] - mx);
    P.gpv[b * 4 + tid] = expf(gvals[tid] - mx) / sum;
  }
}

// second layer, one chain per thread (max parallelism, weights read once per b,
// coalesced). blocks 0..95: sector (b = blk/6, 256-col tile); 96..159: asset.
// Identical ascending-d fmaf chain + identical gumbel indices -> bit-exact.
__device__ __forceinline__ void phase_l2gemm(const Params& P, float* smem,
                                             int blk, int tid) {
  float* h = smem;  // 256
  if (blk < 96) {
    int b = blk / 6, ct = blk % 6;
    h[tid] = P.hgS[b * 256 + tid];
    __syncthreads();
    int col = ct * 256 + tid;
    float acc = P.sb2[col];
    const float* wp = P.sW2 + col;
    #pragma unroll 8
    for (int d = 0; d < 256; ++d) acc = fmaf(h[d], wp[(size_t)d * 1536], acc);
    int f = col / 6, sx = col - f * 6;
    float u = gumbel_u(KS.a, KS.b, (uint32_t)(b * 256 + f) * 6u + sx, 12288u);
    P.lvS[b * 1536 + col] = (acc + (-logf(-logf(u)))) / 0.5f;
  } else {
    int idx = blk - 96;
    int b = idx >> 2, ct = idx & 3;
    h[tid] = P.hgA[b * 256 + tid];
    __syncthreads();
    int col = ct * 256 + tid;
    float acc = P.ab2[col];
    const float* wp = P.aW2 + col;
    #pragma unroll 8
    for (int d = 0; d < 256; ++d) acc = fmaf(h[d], wp[(size_t)d * 1024], acc);
    int f = col >> 2, sx = col & 3;
    float u = gumbel_u(KA.a, KA.b, (uint32_t)(b * 256 + f) * 4u + sx, 8192u);
    P.lvA[b * 1024 + col] = (acc + (-logf(-logf(u)))) / 0.5f;
  }
}

// gate finalize: block = b, thread = feature f. Identical scalar sequence to
// the proven finalize body.
__device__ __forceinline__ void phase_gfin(const Params& P, int b, int tid) {
  int f = tid;
  const float* lvSb = P.lvS + b * 1536 + f * 6;
  float v0 = lvSb[0], v1 = lvSb[1], v2 = lvSb[2];
  float v3 = lvSb[3], v4 = lvSb[4], v5 = lvSb[5];
  float mx = fmaxf(fmaxf(fmaxf(v0, v1), fmaxf(v2, v3)), fmaxf(v4, v5));
  float e0 = expf(v0 - mx), e1 = expf(v1 - mx), e2 = expf(v2 - mx);
  float e3 = expf(v3 - mx), e4 = expf(v4 - mx), e5 = expf(v5 - mx);
  float ssum = e0 + e1 + e2 + e3 + e4 + e5;
  float sg = (e0 / ssum) * P.semb[0 * 256 + f] + (e1 / ssum) * P.semb[1 * 256 + f] +
             (e2 / ssum) * P.semb[2 * 256 + f] + (e3 / ssum) * P.semb[3 * 256 + f] +
             (e4 / ssum) * P.semb[4 * 256 + f] + (e5 / ssum) * P.semb[5 * 256 + f];
  const float* lvAb = P.lvA + b * 1024 + f * 4;
  float a0 = lvAb[0], a1 = lvAb[1], a2 = lvAb[2], a3 = lvAb[3];
  float amx = fmaxf(fmaxf(a0, a1), fmaxf(a2, a3));
  float x0 = expf(a0 - amx), x1 = expf(a1 - amx);
  float x2 = expf(a2 - amx), x3 = expf(a3 - amx);
  float asum = x0 + x1 + x2 + x3;
  float ag = (x0 / asum) * P.aemb[0 * 256 + f] + (x1 / asum) * P.aemb[1 * 256 + f] +
             (x2 / asum) * P.aemb[2 * 256 + f] + (x3 / asum) * P.aemb[3 * 256 + f];
  float gg = 0.f;
  #pragma unroll
  for (int sx = 0; sx < 4; ++sx) gg = fmaf(P.gpv[b * 4 + sx], P.g2f[sx * 256 + f], gg);
  P.fg[b * 256 + f] = sigmoid_f(gg + sg + ag);
}

__device__ __forceinline__ void phase_vcompute(const Params& P, int bid2,
                                               int tid) {
  int j = bid2 >> 2, tg = bid2 & 3;
  const float* wp = (j & 1) ? P.lv_w : P.mean_w;
  const float* Wkk = P.Wk + (size_t)(j >> 1) * 65536;
  int wid = tid >> 6, lane = tid & 63;
  float w0 = wp[lane], w1 = wp[64 + lane];
  float svloc = 0.f;
  for (int i = 0; i < 32; ++i) {
    int t = tg * 128 + wid * 32 + i;
    const float* row = Wkk + (size_t)t * 128;
    float s = row[lane] * w0 + row[64 + lane] * w1;
    s = wave_sum(s);
    if (lane == 0) { P.v[j * 512 + t] = s; svloc += s; }
  }
  if (lane == 0) P.sv[j * 16 + tg * 4 + wid] = svloc;
}

__device__ __forceinline__ void phase_ainit_row(const Params& P, float* smem,
                                                int blk, int tid) {
  float* pn = smem;
  float* s1 = smem + 12;
  float* s2 = smem + 16;
  int mh = blk >> 8, h = mh & 3, n = blk & 255, p = tid;
  if (p < 10) pn[p] = P.psi[(size_t)(h * 256 + n) * 10 + p];
  __syncthreads();
  const float* pp = P.psi + (size_t)(h * 256 + p) * 10;
  float s = 0.f;
  #pragma unroll
  for (int e = 0; e < 10; ++e) s = fmaf(pn[e], pp[e], s);
  float logit = s / sqrtf(10.0f);
  uint32_t idx = (uint32_t)blk * 256u + (uint32_t)p;
  float eps = normal_from(KE.a, KE.b, idx, 524288u);
  float val = logit + expf(P.log_sigma[h]) * eps;
  float mx = blk_max<4>(val, s1);
  float e = expf(val - mx);
  float sum = blk_sum<4>(e, s2);
  P.A[(size_t)blk * 256 + p] = e / sum;
}

__device__ __forceinline__ void phase_ctx(const Params& P, float* smem,
                                          int tid) {
  float* s1 = smem;
  float* s2 = smem + 4;
  float c = 0.f;
  for (int b = 0; b < 16; ++b) c += P.fg[b * 256 + tid];
  c /= 16.0f;
  float ss = blk_sum<4>(c * c, s1);
  float cv = c / (sqrtf(ss) + 1e-6f);
  P.ctx[tid] = cv;
  float S = blk_sum<4>(cv, s2);
  if (tid == 0) P.ctx[256] = S;
}

// tiled transpose of A -> At (32x32 tiles, all accesses coalesced)
__device__ __forceinline__ void phase_transA(const Params& P, float* smem,
                                             int blk, int tid) {
  float* tile = smem;  // 32*33
  int mh = blk >> 6;
  int tr = ((blk >> 3) & 7) * 32, tc = (blk & 7) * 32;
  const float* src = P.A + (size_t)mh * 65536;
  float* dst = P.At + (size_t)mh * 65536;
  int lr = tid >> 5, lc = tid & 31;
  #pragma unroll
  for (int p = 0; p < 4; ++p) {
    int r = p * 8 + lr;
    tile[r * 33 + lc] = src[(size_t)(tr + r) * 256 + tc + lc];
  }
  __syncthreads();
  #pragma unroll
  for (int p = 0; p < 4; ++p) {
    int r = p * 8 + lr;
    dst[(size_t)(tc + r) * 256 + tr + lc] = tile[lc * 33 + r];
  }
}

__device__ __forceinline__ void phase_scan1(const Params& P, float* smem,
                                            int ch, int tid) {
  float* vv = smem;  // [8][32]
  int b = ch >> 4, c = ch & 15;
  int d = tid;
  vv[(d >> 5) * 32 + (d & 31)] = P.v[(d >> 5) * 512 + c * 32 + (d & 31)];
  __syncthreads();
  float g = P.fg[b * 256 + d];
  float af = sigmoid_f(P.decay_f[d]);
  float ab = sigmoid_f(P.decay_b[d]);
  float r_gx[32];
  const float* xp = P.x + ((size_t)b * 512 + c * 32) * 256 + d;
  #pragma unroll
  for (int i = 0; i < 32; ++i) r_gx[i] = xp[(size_t)i * 256] * g;
  float h = 0.f, pw = 1.f;
  float Pr[8], Q[8];
  #pragma unroll
  for (int j = 0; j < 8; ++j) { Pr[j] = 0.f; Q[j] = 0.f; }
  #pragma unroll
  for (int i = 0; i < 32; ++i) {
    h = fmaf(af, h, (1.0f - af) * r_gx[i]);
    pw *= af;
    #pragma unroll
    for (int j = 0; j < 8; ++j) {
      float vj = vv[j * 32 + i];
      Pr[j] = fmaf(h, vj, Pr[j]);
      Q[j] = fmaf(pw, vj, Q[j]);
    }
  }
  size_t base = ((size_t)(b * 16 + c) * 8) * 256 + d;
  #pragma unroll
  for (int j = 0; j < 8; ++j) {
    P.Pf[base + j * 256] = Pr[j];
    P.Qf[base + j * 256] = Q[j];
  }
  P.Lf[(b * 16 + c) * 256 + d] = h;
  h = 0.f; pw = 1.f;
  #pragma unroll
  for (int j = 0; j < 8; ++j) { Pr[j] = 0.f; Q[j] = 0.f; }
  #pragma unroll
  for (int i = 31; i >= 0; --i) {
    h = fmaf(ab, h, (1.0f - ab) * r_gx[i]);
    pw *= ab;
    #pragma unroll
    for (int j = 0; j < 8; ++j) {
      float vj = vv[j * 32 + i];
      Pr[j] = fmaf(h, vj, Pr[j]);
      Q[j] = fmaf(pw, vj, Q[j]);
    }
  }
  #pragma unroll
  for (int j = 0; j < 8; ++j) {
    P.Pb[base + j * 256] = Pr[j];
    P.Qb[base + j * 256] = Q[j];
  }
  P.Lb[(b * 16 + c) * 256 + d] = h;
}

__device__ __forceinline__ void phase_scan2(const Params& P, int blk, int tid) {
  int b = blk >> 3, j = blk & 7;
  int d = tid;
  float af = sigmoid_f(P.decay_f[d]);
  float ab = sigmoid_f(P.decay_b[d]);
  float af32 = af, ab32 = ab;
  #pragma unroll
  for (int q = 0; q < 5; ++q) { af32 *= af32; ab32 *= ab32; }
  float acc = 0.f, H = 0.f;
  for (int c = 0; c < 16; ++c) {
    size_t base = ((size_t)(b * 16 + c) * 8 + j) * 256 + d;
    acc += P.Pf[base] + H * P.Qf[base];
    H = P.Lf[(b * 16 + c) * 256 + d] + af32 * H;
  }
  H = 0.f;
  for (int c = 15; c >= 0; --c) {
    size_t base = ((size_t)(b * 16 + c) * 8 + j) * 256 + d;
    acc += P.Pb[base] + H * P.Qb[base];
    H = P.Lb[(b * 16 + c) * 256 + d] + ab32 * H;
  }
  P.u[(b * 8 + j) * 256 + d] = acc;
}

__device__ __forceinline__ void phase_ygemm(const Params& P, float* smem,
                                            int blk32, int tid) {
  float* As = smem;            // 32*33
  float* Bs = smem + 1056;     // 32*33
  float* svs = smem + 2112;    // 8
  int n0 = (blk32 & 7) * 32, m0 = (blk32 >> 3) * 32;
  int tx = tid & 31, ty = tid >> 5;
  if (tid < 8) {
    float ssv = 0.f;
    #pragma unroll
    for (int q = 0; q < 16; ++q) ssv += P.sv[tid * 16 + q];
    svs[tid] = ssv;
  }
  float acc[4] = {0.f, 0.f, 0.f, 0.f};
  for (int k0 = 0; k0 < 256; k0 += 32) {
    #pragma unroll
    for (int l = 0; l < 4; ++l) {
      int e = tid + l * 256, r = e >> 5, cc = e & 31;
      As[r * 33 + cc] = P.u[(size_t)(m0 + r) * 256 + k0 + cc];
      Bs[r * 33 + cc] = P.tW[(size_t)(k0 + r) * 256 + n0 + cc];
    }
    __syncthreads();
    #pragma unroll
    for (int kk = 0; kk < 32; ++kk) {
      float bv = Bs[kk * 33 + tx];
      #pragma unroll
      for (int i = 0; i < 4; ++i)
        acc[i] = fmaf(As[(ty + 8 * i) * 33 + kk], bv, acc[i]);
    }
    __syncthreads();
  }
  int n = n0 + tx;
  float tbn = P.tb[n];
  float mb0 = P.mean_b[0], lb0 = P.lv_b[0];
  #pragma unroll
  for (int i = 0; i < 4; ++i) {
    int row = m0 + ty + 8 * i;
    int b = row >> 3, j = row & 7;
    float val = acc[i] + tbn * svs[j];
    if (j == 0) P.gm[b * 256 + n] = val + mb0;
    else if (j == 1) P.glv[b * 256 + n] = val + lb0;
    else {
      int k = (j >> 1) - 1, proj = j & 1;
      P.YH[k * 8192 + n * 32 + b * 2 + proj] = val;
    }
  }
}

// tiled symmetric mix: 4-row stripe per block (1024 blocks/mix for occupancy).
template <bool WRITE_T>
__device__ __forceinline__ void phase_mix4(const Params& P, float* smem,
                                           int sidx, const float* Ain,
                                           const float* AinT, float* Aout,
                                           float* AoutT, uint32_t dk0,
                                           uint32_t dk1, int blk, int tid) {
  float* vals = smem;             // 4*257
  float* slots = smem + 4 * 257;  // 4*8
  int mh = blk >> 6, r0 = (blk & 63) * 4;
  float alpha = sigmoid_f(P.step_logits[sidx]);
  float ns = P.noise_scale[sidx];
  float S = P.ctx[256];
  int c = tid;
  float cp = P.ctx[c];
  const size_t mbase = (size_t)mh * 65536;
  #pragma unroll
  for (int r = 0; r < 4; ++r) {
    int n = r0 + r;
    float cn = P.ctx[n];
    float o_np = (cn * cp) / fmaxf(cn * S, 1e-6f);
    float o_pn = (cp * cn) / fmaxf(cp * S, 1e-6f);
    uint32_t i_np = (uint32_t)(mh * 65536 + n * 256 + c);
    uint32_t i_pn = (uint32_t)(mh * 65536 + c * 256 + n);
    float a_np = Ain[mbase + (size_t)n * 256 + c];
    float a_pn = AinT[mbase + (size_t)n * 256 + c];
    float m_np = alpha * a_np + (1.0f - alpha) * o_np +
                 ns * normal_from(dk0, dk1, i_np, 524288u);
    float m_pn = alpha * a_pn + (1.0f - alpha) * o_pn +
                 ns * normal_from(dk0, dk1, i_pn, 524288u);
    vals[r * 257 + c] = 0.5f * (m_np + m_pn);
  }
  __syncthreads();
  #pragma unroll
  for (int r = 0; r < 4; ++r) {
    float val = vals[r * 257 + c];
    float mx = blk_max<4>(val, slots + r * 8);
    float e = expf(val - mx);
    float sum = blk_sum<4>(e, slots + r * 8 + 4);
    float o = e / sum;
    Aout[mbase + (size_t)(r0 + r) * 256 + c] = o;
    if (WRITE_T) vals[r * 257 + c] = o;
  }
  if (WRITE_T) {
    __syncthreads();
    float t0 = vals[0 * 257 + c], t1 = vals[1 * 257 + c];
    float t2 = vals[2 * 257 + c], t3 = vals[3 * 257 + c];
    float4* dst = (float4*)(AoutT + mbase + (size_t)c * 256 + r0);
    dst[0] = make_float4(t0, t1, t2, t3);
  }
}

__device__ __forceinline__ void phase_findec(const Params& P, float* smem,
                                             int bid, int tid) {
  float* gmv = smem;       // 256
  float* sl = smem + 256;  // 20
  int b = bid;
  float sm_ = 0.f, sl_ = 0.f;
  for (int mh = 0; mh < 16; ++mh) {
    sm_ += P.R1[(size_t)mh * 8192 + tid * 32 + b * 2];
    sl_ += P.R1[(size_t)mh * 8192 + tid * 32 + b * 2 + 1];
  }
  float gmn = P.gm[b * 256 + tid] + sm_ * (1.0f / 16.0f);
  float gln = P.glv[b * 256 + tid] + sl_ * (1.0f / 16.0f);
  gmv[tid] = gmn;
  float se = expf(gln);
  __syncthreads();
  float sumexp = blk_sum<4>(se, sl);
  float h = 0.f;
  if (tid < 128) {
    h = P.db1[tid];
    for (int n = 0; n < 256; ++n) h = fmaf(gmv[n], P.dW1[n * 128 + tid], h);
    h = gelu_f(h);
  }
  float mean = blk_sum<4>(tid < 128 ? h : 0.f, sl + 4) / 128.0f;
  float dv = (tid < 128) ? h - mean : 0.f;
  float var = blk_sum<4>(dv * dv, sl + 8) / 128.0f;
  float feat = (tid < 128) ? dv / sqrtf(var + 1e-5f) * P.dlnw[tid] + P.dlnb[tid]
                           : 0.f;
  float m_c = blk_sum<4>(tid < 128 ? feat * P.mW[tid] : 0.f, sl + 12) + P.mb[0];
  float lv_c = blk_sum<4>(tid < 128 ? feat * P.lvW[tid] : 0.f, sl + 16) + P.lvb[0];
  if (tid == 0) {
    P.out[b * 2 + 0] = m_c;
    P.out[b * 2 + 1] = logf(expf(lv_c) + sumexp);
  }
}

// ---------------- launch-level kernels (9 launches) ----------------

// k1: W1 heads (0..47) | vcompute (48..79) | ainit (80..4175)
__global__ __launch_bounds__(256) void kA(Params P) {
  __shared__ float smem[288];
  int bid = blockIdx.x, tid = threadIdx.x;
  if (bid < 48) phase_w1head(P, smem, bid, tid);
  else if (bid < 80) phase_vcompute(P, bid - 48, tid);
  else phase_ainit_row(P, smem, bid - 80, tid);
}

// k2: second-layer GEMM (0..159) | transA first half (160..671 -> blk 0..511)
__global__ __launch_bounds__(256) void kL2(Params P) {
  __shared__ float smem[1056];
  int bid = blockIdx.x, tid = threadIdx.x;
  if (bid < 160) phase_l2gemm(P, smem, bid, tid);
  else phase_transA(P, smem, bid - 160, tid);
}

// k3: gate finalize (0..15) | transA second half (16..527 -> blk 512..1023)
__global__ __launch_bounds__(256) void kGF(Params P) {
  __shared__ float smem[1056];
  int bid = blockIdx.x, tid = threadIdx.x;
  if (bid < 16) phase_gfin(P, bid, tid);
  else phase_transA(P, smem, bid - 16 + 512, tid);
}

// k4: scan1(0..255) | ctx(256)
__global__ __launch_bounds__(256) void kScan(Params P) {
  __shared__ float smem[256];
  int bid = blockIdx.x, tid = threadIdx.x;
  if (bid < 256) phase_scan1(P, smem, bid, tid);
  else phase_ctx(P, smem, tid);
}

// k5: mix0 stripes (0..1023) | scan2 (1024..1151)
__global__ __launch_bounds__(256) void kM0(Params P) {
  __shared__ float smem[1060];
  int bid = blockIdx.x, tid = threadIdx.x;
  if (bid < 1024)
    phase_mix4<true>(P, smem, 0, P.A, P.At, P.A2, P.At2, DK0.a, DK0.b, bid, tid);
  else
    phase_scan2(P, bid - 1024, tid);
}

// k6: mix1 stripes (0..1023) | ygemm (1024..1055)
__global__ __launch_bounds__(256) void kM1(Params P) {
  __shared__ float smem[2120];
  int bid = blockIdx.x, tid = threadIdx.x;
  if (bid < 1024)
    phase_mix4<true>(P, smem, 1, P.A2, P.At2, P.A, P.At, DK1.a, DK1.b, bid, tid);
  else
    phase_ygemm(P, smem, bid - 1024, tid);
}

// k7: mix2 stripes (1024) — no transpose output (horner reads rows only)
__global__ __launch_bounds__(256) void kM2(Params P) {
  __shared__ float smem[1060];
  phase_mix4<false>(P, smem, 2, P.A, P.At, P.A2, nullptr, DK2.a, DK2.b,
                    blockIdx.x, threadIdx.x);
}

// k8: fused 3-hop horner (bit-exact chains, R columns in LDS across hops)
__global__ __launch_bounds__(256) void kHor(Params P) {
  __shared__ float Rc[512];  // [256 k][2 c]
  int bid = blockIdx.x, tid = threadIdx.x;
  int mh = bid >> 4, c0 = (bid & 15) * 2;
  const float* Ab = P.A2 + (size_t)mh * 65536;
  const float4* Arow = (const float4*)(Ab + (size_t)tid * 256);
  const float* Y2 = P.YH + 2 * 8192;
  Rc[tid * 2 + 0] = Y2[tid * 32 + c0 + 0];
  Rc[tid * 2 + 1] = Y2[tid * 32 + c0 + 1];
  __syncthreads();
  #pragma unroll
  for (int hop = 0; hop < 3; ++hop) {
    float acc0 = 0.f, acc1 = 0.f;
    const float4* Rc4 = (const float4*)Rc;
    for (int k4 = 0; k4 < 64; ++k4) {
      float4 a = Arow[k4];
      float4 r01 = Rc4[k4 * 2];
      float4 r23 = Rc4[k4 * 2 + 1];
      acc0 = fmaf(a.x, r01.x, acc0); acc1 = fmaf(a.x, r01.y, acc1);
      acc0 = fmaf(a.y, r01.z, acc0); acc1 = fmaf(a.y, r01.w, acc1);
      acc0 = fmaf(a.z, r23.x, acc0); acc1 = fmaf(a.z, r23.y, acc1);
      acc0 = fmaf(a.w, r23.z, acc0); acc1 = fmaf(a.w, r23.w, acc1);
    }
    if (hop == 0) {
      acc0 += P.YH[8192 + tid * 32 + c0 + 0];
      acc1 += P.YH[8192 + tid * 32 + c0 + 1];
    } else if (hop == 1) {
      acc0 += P.YH[tid * 32 + c0 + 0];
      acc1 += P.YH[tid * 32 + c0 + 1];
    }
    __syncthreads();
    Rc[tid * 2 + 0] = acc0;
    Rc[tid * 2 + 1] = acc1;
    __syncthreads();
  }
  P.R1[(size_t)mh * 8192 + (size_t)tid * 32 + c0 + 0] = Rc[tid * 2 + 0];
  P.R1[(size_t)mh * 8192 + (size_t)tid * 32 + c0 + 1] = Rc[tid * 2 + 1];
}

// k9: final + decoder (16 blocks)
__global__ __launch_bounds__(256) void kFin(Params P) {
  __shared__ float smem[276];
  phase_findec(P, smem, blockIdx.x, threadIdx.x);
}

// workspace layout (float offsets)
constexpr size_t O_FG = 0;            // 4096
constexpr size_t O_CTX = 4096;        // 384 (uses 257)
constexpr size_t O_V = 4480;          // 4096
constexpr size_t O_SV = 8576;         // 128 (per-wave partials)
constexpr size_t O_U = 8704;          // 32768
constexpr size_t O_PF = 41472;        // 524288
constexpr size_t O_QF = 565760;       // 524288
constexpr size_t O_PB = 1090048;      // 524288
constexpr size_t O_QB = 1614336;      // 524288
constexpr size_t O_LF = 2138624;      // 65536
constexpr size_t O_LB = 2204160;      // 65536
constexpr size_t O_YH = 2269696;      // 24576
constexpr size_t O_R1 = 2294272;      // 131072
constexpr size_t O_GM = 2425344;      // 4096
constexpr size_t O_GLV = 2429440;     // 4096
constexpr size_t O_A = 2433536;       // 1048576
constexpr size_t O_A2 = 3482112;      // 1048576
constexpr size_t O_AT = 4530688;      // 1048576
constexpr size_t O_AT2 = 5579264;     // 1048576
constexpr size_t O_HGS = 6627840;     // 4096
constexpr size_t O_HGA = 6631936;     // 4096
constexpr size_t O_LVS = 6636032;     // 24576
constexpr size_t O_LVA = 6660608;     // 16384
constexpr size_t O_GPV = 6676992;     // 64
// end = 6677056 floats ~= 26.7 MB

}  // namespace

extern "C" void kernel_launch(void* const* d_in, const int* in_sizes, int n_in,
                              void* d_out, int out_size, void* d_ws,
                              size_t ws_size, hipStream_t stream) {
  (void)in_sizes; (void)n_in; (void)out_size; (void)ws_size;
  float* w = (float*)d_ws;
  Params prm;
  prm.x = (const float*)d_in[0];
  prm.gW1 = (const float*)d_in[1];
  prm.gb1 = (const float*)d_in[2];
  prm.glnw = (const float*)d_in[3];
  prm.glnb = (const float*)d_in[4];
  prm.gW2 = (const float*)d_in[5];
  prm.gb2 = (const float*)d_in[6];
  prm.sW1 = (const float*)d_in[7];
  prm.sb1 = (const float*)d_in[8];
  prm.sW2 = (const float*)d_in[9];
  prm.sb2 = (const float*)d_in[10];
  prm.aW1 = (const float*)d_in[11];
  prm.ab1 = (const float*)d_in[12];
  prm.aW2 = (const float*)d_in[13];
  prm.ab2 = (const float*)d_in[14];
  prm.g2f = (const float*)d_in[18];
  prm.semb = (const float*)d_in[19];
  prm.aemb = (const float*)d_in[20];
  prm.decay_f = (const float*)d_in[21];
  prm.decay_b = (const float*)d_in[22];
  prm.tW = (const float*)d_in[23];
  prm.tb = (const float*)d_in[24];
  prm.psi = (const float*)d_in[25];
  prm.log_sigma = (const float*)d_in[26];
  prm.step_logits = (const float*)d_in[27];
  prm.noise_scale = (const float*)d_in[28];
  prm.Wk = (const float*)d_in[29];
  prm.mean_w = (const float*)d_in[30];
  prm.mean_b = (const float*)d_in[31];
  prm.lv_w = (const float*)d_in[32];
  prm.lv_b = (const float*)d_in[33];
  prm.dW1 = (const float*)d_in[34];
  prm.db1 = (const float*)d_in[35];
  prm.dlnw = (const float*)d_in[36];
  prm.dlnb = (const float*)d_in[37];
  prm.mW = (const float*)d_in[38];
  prm.mb = (const float*)d_in[39];
  prm.lvW = (const float*)d_in[40];
  prm.lvb = (const float*)d_in[41];
  prm.out = (float*)d_out;
  prm.fg = w + O_FG;
  prm.ctx = w + O_CTX;
  prm.v = w + O_V;
  prm.sv = w + O_SV;
  prm.u = w + O_U;
  prm.Pf = w + O_PF;
  prm.Qf = w + O_QF;
  prm.Pb = w + O_PB;
  prm.Qb = w + O_QB;
  prm.Lf = w + O_LF;
  prm.Lb = w + O_LB;
  prm.YH = w + O_YH;
  prm.R1 = w + O_R1;
  prm.gm = w + O_GM;
  prm.glv = w + O_GLV;
  prm.A = w + O_A;
  prm.A2 = w + O_A2;
  prm.At = w + O_AT;
  prm.At2 = w + O_AT2;
  prm.hgS = w + O_HGS;
  prm.hgA = w + O_HGA;
  prm.lvS = w + O_LVS;
  prm.lvA = w + O_LVA;
  prm.gpv = w + O_GPV;

  kA<<<4176, 256, 0, stream>>>(prm);
  kL2<<<672, 256, 0, stream>>>(prm);
  kGF<<<528, 256, 0, stream>>>(prm);
  kScan<<<257, 256, 0, stream>>>(prm);
  kM0<<<1152, 256, 0, stream>>>(prm);
  kM1<<<1056, 256, 0, stream>>>(prm);
  kM2<<<1024, 256, 0, stream>>>(prm);
  kHor<<<256, 256, 0, stream>>>(prm);
  kFin<<<16, 256, 0, stream>>>(prm);
}